// Round 1
// baseline (155.660 us; speedup 1.0000x reference)
//
#include <hip/hip_runtime.h>
#include <math.h>

#define N 1024
#define D 256
#define EPSF 1e-8f

// Kernel 1: per-row L2 norm of X[1024][256], then y[i] = X[i][0] / max(norm, eps).
__global__ void __launch_bounds__(256) rownorm_kernel(const float* __restrict__ X,
                                                      float* __restrict__ y) {
    const int row = blockIdx.x;
    const int tid = threadIdx.x;
    float v = X[row * D + tid];
    float ss = v * v;

    // wave (64-lane) shuffle reduce, then LDS across the 4 waves
    #pragma unroll
    for (int off = 32; off > 0; off >>= 1)
        ss += __shfl_down(ss, off, 64);

    __shared__ float wsum[4];
    const int wave = tid >> 6;
    const int lane = tid & 63;
    if (lane == 0) wsum[wave] = ss;
    __syncthreads();

    if (tid == 0) {
        float total = wsum[0] + wsum[1] + wsum[2] + wsum[3];
        float norm = sqrtf(total);
        float denom = fmaxf(norm, EPSF);
        y[row] = X[row * D] / denom;
    }
}

// Kernel 2: m_i = min_{j != i} |y_j - y_i|; out = sum(-log(m_i+eps))/N - 255*log(eps)
__global__ void __launch_bounds__(1024) koleo_kernel(const float* __restrict__ y,
                                                     float* __restrict__ out) {
    __shared__ float sy[N];
    const int tid = threadIdx.x;
    sy[tid] = y[tid];
    __syncthreads();

    const float yi = sy[tid];
    float m = INFINITY;
    #pragma unroll 8
    for (int j = 0; j < N; ++j) {
        float d = fabsf(sy[j] - yi);
        d = (j == tid) ? INFINITY : d;
        m = fminf(m, d);
    }
    float val = -logf(m + EPSF);

    // block reduction: wave shuffle then LDS tree over 16 waves
    #pragma unroll
    for (int off = 32; off > 0; off >>= 1)
        val += __shfl_down(val, off, 64);

    __shared__ float wsum[16];
    const int wave = tid >> 6;
    const int lane = tid & 63;
    if (lane == 0) wsum[wave] = val;
    __syncthreads();

    if (tid == 0) {
        float total = 0.0f;
        #pragma unroll
        for (int w = 0; w < 16; ++w) total += wsum[w];
        // k>=1 features: m == 0 exactly, contributing -(d-1)*log(eps) after /n
        out[0] = total * (1.0f / (float)N) - 255.0f * logf(EPSF);
    }
}

extern "C" void kernel_launch(void* const* d_in, const int* in_sizes, int n_in,
                              void* d_out, int out_size, void* d_ws, size_t ws_size,
                              hipStream_t stream) {
    const float* X = (const float*)d_in[0];
    float* out = (float*)d_out;
    float* y = (float*)d_ws;  // 1024 floats = 4 KB scratch

    rownorm_kernel<<<N, D, 0, stream>>>(X, y);
    koleo_kernel<<<1, N, 0, stream>>>(y, out);
}

// Round 2
// 60.612 us; speedup vs baseline: 2.5681x; 2.5681x over previous
//
#include <hip/hip_runtime.h>
#include <math.h>

#define N 1024
#define D 256
#define EPSF 1e-8f
#define K2_BLOCKS 128

// Kernel 1: per-row L2 norm of X[1024][256]; y[i] = X[i][0]/max(||X_i||,eps).
// One 64-lane wave per row, float4 loads (16B/lane = one full 1KB row per wave).
// Block 0 also zeroes the accumulator + ticket counter for kernel 2.
__global__ void __launch_bounds__(256) rownorm_kernel(const float* __restrict__ X,
                                                      float* __restrict__ y,
                                                      float* __restrict__ accum,
                                                      int* __restrict__ cnt) {
    const int tid  = threadIdx.x;
    const int wave = tid >> 6;
    const int lane = tid & 63;
    const int row  = blockIdx.x * 4 + wave;

    const float4 v = ((const float4*)(X + row * D))[lane];
    float ss = v.x * v.x + v.y * v.y + v.z * v.z + v.w * v.w;
    #pragma unroll
    for (int off = 32; off > 0; off >>= 1)
        ss += __shfl_down(ss, off, 64);

    if (lane == 0) {
        // lane 0's v.x is X[row*D + 0]
        y[row] = v.x / fmaxf(sqrtf(ss), EPSF);
    }
    if (blockIdx.x == 0 && tid == 0) { *accum = 0.0f; *cnt = 0; }
}

// Kernel 2: m_i = min_{j != i} |y_j - y_i|; partial sums of -log(m_i+eps)
// atomically accumulated; last block finalizes out.
// 128 blocks x 256 threads; 32 threads cooperate per row i (8 rows/block).
__global__ void __launch_bounds__(256) koleo_kernel(const float* __restrict__ y,
                                                    float* __restrict__ accum,
                                                    int* __restrict__ cnt,
                                                    float* __restrict__ out) {
    __shared__ float sy[N];
    const int tid = threadIdx.x;
    ((float4*)sy)[tid] = ((const float4*)y)[tid];
    __syncthreads();

    const int grp = tid >> 5;        // 0..7 : which row within this block
    const int s   = tid & 31;        // 0..31: sublane within the row group
    const int i   = blockIdx.x * 8 + grp;
    const float yi = sy[i];

    float m = INFINITY;
    #pragma unroll 8
    for (int t = 0; t < 32; ++t) {
        const int j = s + (t << 5);          // covers 0..1023, stride-32 per lane
        float d = fabsf(sy[j] - yi);
        d = (j == i) ? INFINITY : d;
        m = fminf(m, d);
    }
    // min across the 32-lane subgroup (xor masks < 32 stay within subgroup)
    #pragma unroll
    for (int off = 16; off > 0; off >>= 1)
        m = fminf(m, __shfl_xor(m, off, 64));

    float val = (s == 0) ? -logf(m + EPSF) : 0.0f;
    // sum across the full 64-lane wave (picks up both subgroups' s==0 lanes)
    #pragma unroll
    for (int off = 32; off > 0; off >>= 1)
        val += __shfl_down(val, off, 64);

    __shared__ float wsum[4];
    if ((tid & 63) == 0) wsum[tid >> 6] = val;
    __syncthreads();

    if (tid == 0) {
        const float part = wsum[0] + wsum[1] + wsum[2] + wsum[3];
        atomicAdd(accum, part);
        __threadfence();
        const int ticket = atomicAdd(cnt, 1);
        if (ticket == K2_BLOCKS - 1) {
            // atomic RMW read: coherent with the other blocks' atomicAdds
            const float total = atomicAdd(accum, 0.0f);
            // k>=1 features contribute exactly -(d-1)*log(eps) after /n
            out[0] = total * (1.0f / (float)N) - 255.0f * logf(EPSF);
        }
    }
}

extern "C" void kernel_launch(void* const* d_in, const int* in_sizes, int n_in,
                              void* d_out, int out_size, void* d_ws, size_t ws_size,
                              hipStream_t stream) {
    const float* X = (const float*)d_in[0];
    float* out = (float*)d_out;
    float* y     = (float*)d_ws;              // [0..1023]
    float* accum = (float*)d_ws + N;          // [1024]
    int*   cnt   = (int*)((float*)d_ws + N + 1); // [1025]

    rownorm_kernel<<<N / 4, 256, 0, stream>>>(X, y, accum, cnt);
    koleo_kernel<<<K2_BLOCKS, 256, 0, stream>>>(y, accum, cnt, out);
}